// Round 1
// baseline (610.383 us; speedup 1.0000x reference)
//
#include <hip/hip_runtime.h>
#include <math.h>

// mLSTM parallel form:
//   F_t = prefix_sum(log_sigmoid(f)),  b_s = i_s - F_s,
//   M_t = max(0, prefix_max(b)_t),  m_t = F_t + M_t,
//   w[t,s] = exp(b_s - M_t)  (s <= t, always <= 1),
//   h_num_t = sum_s w*(q_t.k_s)*v_s,  qn_t = sum_s w*(q_t.k_s),
//   h_t = h_num_t / (max(|qn_t|, exp(-m_t)) + 1e-6)

#define S_LEN 2048
#define DHD   128
#define NHEADS 8     // B*NH = 2*4
#define QT    32
#define KT    64
#define LROW  132    // padded LDS row (floats): keeps ds_read_b128 <=2-way conflicted
#define LPAD  68

// ---------------- scan kernel: F (prefix sum), b, M (prefix max) in fp64 ----
__global__ __launch_bounds__(256) void mlstm_scan(
    const float* __restrict__ ig_all, const float* __restrict__ fg_all,
    double* __restrict__ Fd, double* __restrict__ Bd, double* __restrict__ Md)
{
  const int hd  = blockIdx.x;   // 0..7
  const int tid = threadIdx.x;  // 256 threads, 8 elements each
  __shared__ double sc[256];
  const float* fg = fg_all + (size_t)hd * S_LEN;
  const float* ig = ig_all + (size_t)hd * S_LEN;
  const int base = tid * 8;

  double v[8];
#pragma unroll
  for (int u = 0; u < 8; ++u) {
    float x = fg[base + u];
    float fl = fminf(x, 0.0f) - log1pf(expf(-fabsf(x)));  // log_sigmoid, stable
    v[u] = (double)fl;
  }
#pragma unroll
  for (int u = 1; u < 8; ++u) v[u] += v[u - 1];
  sc[tid] = v[7];
  __syncthreads();
  for (int off = 1; off < 256; off <<= 1) {   // Hillis-Steele inclusive sum
    double t = (tid >= off) ? sc[tid - off] : 0.0;
    __syncthreads();
    sc[tid] += t;
    __syncthreads();
  }
  const double excl = sc[tid] - v[7];

  double b[8];
#pragma unroll
  for (int u = 0; u < 8; ++u) {
    double Fu = v[u] + excl;
    Fd[(size_t)hd * S_LEN + base + u] = Fu;
    double bu = (double)ig[base + u] - Fu;
    Bd[(size_t)hd * S_LEN + base + u] = bu;
    b[u] = bu;
  }
  __syncthreads();

  double mv[8];
  mv[0] = b[0];
#pragma unroll
  for (int u = 1; u < 8; ++u) mv[u] = fmax(mv[u - 1], b[u]);
  sc[tid] = mv[7];
  __syncthreads();
  for (int off = 1; off < 256; off <<= 1) {   // Hillis-Steele inclusive max
    double t = (tid >= off) ? sc[tid - off] : -1.0e300;
    __syncthreads();
    sc[tid] = fmax(sc[tid], t);
    __syncthreads();
  }
  const double exclm = (tid > 0) ? sc[tid - 1] : -1.0e300;
#pragma unroll
  for (int u = 0; u < 8; ++u) {
    // seed 0 accounts for the m0=0 carry path in the reference recurrence
    Md[(size_t)hd * S_LEN + base + u] = fmax(0.0, fmax(exclm, mv[u]));
  }
}

// ---------------- main kernel: flash-style causal weighted attention --------
__global__ __launch_bounds__(256) void mlstm_main(
    const float* __restrict__ qg, const float* __restrict__ kg, const float* __restrict__ vg,
    const double* __restrict__ Fd, const double* __restrict__ Bd, const double* __restrict__ Md,
    float* __restrict__ outg)
{
  __shared__ float  Qs[QT][LROW];
  __shared__ float  Ks[KT][LROW];
  __shared__ float  Vs[KT][LROW];
  __shared__ float  Ps[QT][LPAD];
  __shared__ double bcol[KT];
  __shared__ double Mrow[QT];
  __shared__ float  dmin[QT];

  const int hd = blockIdx.y;           // head 0..7
  const int j  = blockIdx.x;           // 0..63
  const int qt = 63 - j;               // largest causal workload dispatched first
  const int t0 = qt * QT;
  const int tid = threadIdx.x;
  const int ty = tid >> 4;             // 0..15: row group (rows ty, ty+16)
  const int tx = tid & 15;             // 0..15: col group (cols tx+16*jc / e=4tx)

  const float* qh = qg + ((size_t)hd * S_LEN + t0) * DHD;
  const float* kh = kg + (size_t)hd * S_LEN * DHD;
  const float* vh = vg + (size_t)hd * S_LEN * DHD;

  constexpr float QSC = 0.08838834764831845f;  // 128^-0.5
  for (int idx = tid; idx < QT * DHD / 4; idx += 256) {
    const int r  = idx >> 5;
    const int d4 = (idx & 31) << 2;
    float4 t = *(const float4*)(qh + (size_t)r * DHD + d4);
    t.x *= QSC; t.y *= QSC; t.z *= QSC; t.w *= QSC;
    *(float4*)&Qs[r][d4] = t;
  }
  if (tid < QT) {
    const size_t gi = (size_t)hd * S_LEN + t0 + tid;
    const double m_t = Fd[gi] + Md[gi];
    Mrow[tid] = Md[gi];
    dmin[tid] = expf((float)(-m_t));
  }

  float ha[2][8];
#pragma unroll
  for (int a = 0; a < 2; ++a)
#pragma unroll
    for (int e = 0; e < 8; ++e) ha[a][e] = 0.0f;
  float qn[2] = {0.0f, 0.0f};

  const int tlast = t0 + QT - 1;
  for (int s0 = 0; s0 <= tlast; s0 += KT) {
    __syncthreads();   // previous iteration's PV reads done before overwrite
    for (int idx = tid; idx < KT * DHD / 4; idx += 256) {
      const int r  = idx >> 5;
      const int d4 = (idx & 31) << 2;
      *(float4*)&Ks[r][d4] = *(const float4*)(kh + (size_t)(s0 + r) * DHD + d4);
      *(float4*)&Vs[r][d4] = *(const float4*)(vh + (size_t)(s0 + r) * DHD + d4);
    }
    if (tid < KT) bcol[tid] = Bd[(size_t)hd * S_LEN + s0 + tid];
    __syncthreads();

    // ---- S = Q.K^T  (2 rows x 4 cols per thread) ----
    float acc[2][4];
#pragma unroll
    for (int a = 0; a < 2; ++a)
#pragma unroll
      for (int c = 0; c < 4; ++c) acc[a][c] = 0.0f;

#pragma unroll 4
    for (int d4 = 0; d4 < DHD; d4 += 4) {
      const float4 q0 = *(const float4*)&Qs[ty][d4];
      const float4 q1 = *(const float4*)&Qs[ty + 16][d4];
#pragma unroll
      for (int jc = 0; jc < 4; ++jc) {
        const float4 kv = *(const float4*)&Ks[tx + 16 * jc][d4];
        acc[0][jc] += q0.x * kv.x + q0.y * kv.y + q0.z * kv.z + q0.w * kv.w;
        acc[1][jc] += q1.x * kv.x + q1.y * kv.y + q1.z * kv.z + q1.w * kv.w;
      }
    }

    // ---- weights: P = exp(b_s - M_t) * S, causal mask; accumulate qn ----
#pragma unroll
    for (int jr = 0; jr < 2; ++jr) {
      const int r  = ty + 16 * jr;
      const int tg = t0 + r;
      const double Mr = Mrow[r];
#pragma unroll
      for (int jc = 0; jc < 4; ++jc) {
        const int c  = tx + 16 * jc;
        const int sg = s0 + c;
        float p = 0.0f;
        if (sg <= tg) p = expf((float)(bcol[c] - Mr)) * acc[jr][jc];
        Ps[r][c] = p;
        qn[jr] += p;
      }
    }
    __syncthreads();

    // ---- PV: h += P.V  (2 rows x 8 e-cols per thread) ----
#pragma unroll 4
    for (int c4 = 0; c4 < KT; c4 += 4) {
      const float4 p0 = *(const float4*)&Ps[ty][c4];
      const float4 p1 = *(const float4*)&Ps[ty + 16][c4];
#pragma unroll
      for (int cc = 0; cc < 4; ++cc) {
        const float4 va = *(const float4*)&Vs[c4 + cc][tx * 4];
        const float4 vb = *(const float4*)&Vs[c4 + cc][tx * 4 + 64];
        const float pa = (cc == 0) ? p0.x : (cc == 1) ? p0.y : (cc == 2) ? p0.z : p0.w;
        const float pb = (cc == 0) ? p1.x : (cc == 1) ? p1.y : (cc == 2) ? p1.z : p1.w;
        ha[0][0] += pa * va.x; ha[0][1] += pa * va.y; ha[0][2] += pa * va.z; ha[0][3] += pa * va.w;
        ha[0][4] += pa * vb.x; ha[0][5] += pa * vb.y; ha[0][6] += pa * vb.z; ha[0][7] += pa * vb.w;
        ha[1][0] += pb * va.x; ha[1][1] += pb * va.y; ha[1][2] += pb * va.z; ha[1][3] += pb * va.w;
        ha[1][4] += pb * vb.x; ha[1][5] += pb * vb.y; ha[1][6] += pb * vb.z; ha[1][7] += pb * vb.w;
      }
    }
  }

  // ---- epilogue: reduce qn across the 16-lane column group, normalize ----
#pragma unroll
  for (int off = 1; off < 16; off <<= 1) {
    qn[0] += __shfl_xor(qn[0], off);
    qn[1] += __shfl_xor(qn[1], off);
  }
  float* oh = outg + ((size_t)hd * S_LEN + t0) * DHD;
#pragma unroll
  for (int jr = 0; jr < 2; ++jr) {
    const int r = ty + 16 * jr;
    const float den = fmaxf(fabsf(qn[jr]), dmin[r]) + 1e-6f;
    const float inv = 1.0f / den;
    float4 o0 = make_float4(ha[jr][0] * inv, ha[jr][1] * inv, ha[jr][2] * inv, ha[jr][3] * inv);
    float4 o1 = make_float4(ha[jr][4] * inv, ha[jr][5] * inv, ha[jr][6] * inv, ha[jr][7] * inv);
    *(float4*)(oh + (size_t)r * DHD + tx * 4)      = o0;
    *(float4*)(oh + (size_t)r * DHD + tx * 4 + 64) = o1;
  }
}

extern "C" void kernel_launch(void* const* d_in, const int* in_sizes, int n_in,
                              void* d_out, int out_size, void* d_ws, size_t ws_size,
                              hipStream_t stream) {
  (void)in_sizes; (void)n_in; (void)out_size; (void)ws_size;
  const float* q  = (const float*)d_in[0];
  const float* k  = (const float*)d_in[1];
  const float* v  = (const float*)d_in[2];
  const float* ii = (const float*)d_in[3];
  const float* ff = (const float*)d_in[4];
  float* out = (float*)d_out;

  // workspace: 3 fp64 arrays of NHEADS*S_LEN (384 KiB total)
  double* Fd = (double*)d_ws;
  double* Bd = Fd + (size_t)NHEADS * S_LEN;
  double* Md = Bd + (size_t)NHEADS * S_LEN;

  mlstm_scan<<<dim3(NHEADS), dim3(256), 0, stream>>>(ii, ff, Fd, Bd, Md);
  mlstm_main<<<dim3(64, NHEADS), dim3(256), 0, stream>>>(q, k, v, Fd, Bd, Md, out);
}

// Round 3
// 166.331 us; speedup vs baseline: 3.6697x; 3.6697x over previous
//
#include <hip/hip_runtime.h>
#include <math.h>

// mLSTM parallel closed form:
//   F_t = prefix_sum(log_sigmoid(f)),  b_s = i_s - F_s,
//   M_t = max(0, prefix_max(b)_t),  m_t = F_t + M_t,
//   w[t,s] = exp(b_s - M_t)  (s <= t, always <= 1),
//   h_t = (sum_s w*(q.k_s)*v_s) / (max(|sum_s w*(q.k_s)|, exp(-m_t)) + 1e-6)
//
// Engine: split-fp16 MFMA (x = hi+lo, 3 mfma per fp32 product) on
// v_mfma_f32_16x16x32_f16. Swapped QK^T (A=K, B=Q) so P stays in-register
// for PV's A-operand; V staged transposed in LDS with the matching k-sigma.

typedef _Float16 f16;
typedef _Float16 f16x4 __attribute__((ext_vector_type(4)));
typedef _Float16 f16x8 __attribute__((ext_vector_type(8)));
typedef float    f32x4 __attribute__((ext_vector_type(4)));

#define S_LEN  2048
#define DHD    128
#define NHEADS 8
#define QT     32      // q rows per block
#define KT     128     // kv rows per iteration (32 per wave)
#define EPS    1e-6f

// LDS byte offsets
#define KH_OFF  0          // fp16 [128][128] K hi
#define KL_OFF  32768      // fp16 [128][128] K lo
#define VTH_OFF 65536      // fp16 [128 e][128 kv] V^T hi
#define VTL_OFF 98304      // fp16 [128 e][128 kv] V^T lo
#define BS_OFF  131072     // f32 [128] b_s tile
#define QNL_OFF 131712     // f32 [4][32] per-wave qn partials
#define SMEM_BYTES 132224
#define PART_OFF 0         // epilogue: f32 [4 waves][32 q][132] partials (67.6 KB)

__device__ __forceinline__ int kswz(int row, int byteInRow) {
  // row-major [kv][d] fp16, row = 256 B; XOR-swizzle kills 256B-stride conflicts
  return row * 256 + (byteInRow ^ ((row & 15) << 4));
}
__device__ __forceinline__ int vswz(int e, int byteInRow) {
  // transposed [e][kv] fp16; extra bit-3 flip separates e vs e+16 on writes
  return e * 256 + (byteInRow ^ ((e & 15) << 4) ^ (((e >> 4) & 1) << 3));
}

__device__ __forceinline__ f32x4 mfma16(f16x8 a, f16x8 b, f32x4 c) {
  return __builtin_amdgcn_mfma_f32_16x16x32_f16(a, b, c, 0, 0, 0);
}

// ---------------- scan prepass: b_s, M_t, exp(-m_t) (fp64 internal) --------
__global__ __launch_bounds__(256) void mlstm_scan(
    const float* __restrict__ ig_all, const float* __restrict__ fg_all,
    float* __restrict__ bf, float* __restrict__ Mf, float* __restrict__ en)
{
  const int hd  = blockIdx.x;
  const int tid = threadIdx.x;
  __shared__ double sc[256];
  const float* fg = fg_all + (size_t)hd * S_LEN;
  const float* ig = ig_all + (size_t)hd * S_LEN;
  const int base = tid * 8;

  double v[8];
#pragma unroll
  for (int u = 0; u < 8; ++u) {
    float x = fg[base + u];
    float fl = fminf(x, 0.0f) - log1pf(expf(-fabsf(x)));  // stable log_sigmoid
    v[u] = (double)fl;
  }
#pragma unroll
  for (int u = 1; u < 8; ++u) v[u] += v[u - 1];
  sc[tid] = v[7];
  __syncthreads();
  for (int off = 1; off < 256; off <<= 1) {
    double t = (tid >= off) ? sc[tid - off] : 0.0;
    __syncthreads();
    sc[tid] += t;
    __syncthreads();
  }
  const double excl = sc[tid] - v[7];

  double F[8], b[8];
#pragma unroll
  for (int u = 0; u < 8; ++u) {
    F[u] = v[u] + excl;
    b[u] = (double)ig[base + u] - F[u];
    bf[(size_t)hd * S_LEN + base + u] = (float)b[u];
  }
  __syncthreads();
  double mv[8];
  mv[0] = b[0];
#pragma unroll
  for (int u = 1; u < 8; ++u) mv[u] = fmax(mv[u - 1], b[u]);
  sc[tid] = mv[7];
  __syncthreads();
  for (int off = 1; off < 256; off <<= 1) {
    double t = (tid >= off) ? sc[tid - off] : -1.0e300;
    __syncthreads();
    sc[tid] = fmax(sc[tid], t);
    __syncthreads();
  }
  const double exclm = (tid > 0) ? sc[tid - 1] : -1.0e300;
  double run = exclm;
#pragma unroll
  for (int u = 0; u < 8; ++u) {
    run = fmax(run, b[u]);            // inclusive prefix max
    double Mt = fmax(0.0, run);       // m0=0 carry path
    Mf[(size_t)hd * S_LEN + base + u] = (float)Mt;
    en[(size_t)hd * S_LEN + base + u] = (float)exp(-(F[u] + Mt));
  }
}

// ---------------- main kernel: MFMA flash-style causal weighted attention ---
__global__ __launch_bounds__(256, 1) void mlstm_main(
    const float* __restrict__ qg, const float* __restrict__ kg, const float* __restrict__ vg,
    const float* __restrict__ bf, const float* __restrict__ Mf, const float* __restrict__ en,
    float* __restrict__ outg)
{
  extern __shared__ char smem[];
  const int bid  = blockIdx.x;
  const int hd   = bid & 7;            // round-robin heads across consecutive bids
  const int qt32 = 63 - (bid >> 3);    // biggest causal workload dispatched first
  const int t0   = qt32 * QT;
  const int tid  = threadIdx.x;
  const int w    = tid >> 6;           // wave 0..3 (owns kv chunk 32w..32w+31)
  const int lane = tid & 63;
  const int c    = lane & 15;          // MFMA m/n lane index
  const int g    = lane >> 4;          // lane group

  const size_t hbase = (size_t)hd * S_LEN;
  const float* qg_h = qg + (hbase + t0) * DHD;
  const float* kg_h = kg + hbase * DHD;
  const float* vg_h = vg + hbase * DHD;
  float* bs_lds = (float*)(smem + BS_OFF);

  // ---- Q fragments in registers (hi/lo split), scaled by DH^-0.5 ----
  // B-frag: n = c (q row), k = kc*32 + 8g + s  (sigma_k, shared with K A-frag)
  constexpr float QSC = 0.08838834764831845f;
  f16x8 qfh[2][4], qfl[2][4];
#pragma unroll
  for (int qt = 0; qt < 2; ++qt) {
    const float* qrow = qg_h + (size_t)(16 * qt + c) * DHD;
#pragma unroll
    for (int kc = 0; kc < 4; ++kc) {
      const float* p = qrow + kc * 32 + 8 * g;
      float4 a = *(const float4*)p;
      float4 b = *(const float4*)(p + 4);
      float xs[8] = {a.x, a.y, a.z, a.w, b.x, b.y, b.z, b.w};
#pragma unroll
      for (int s = 0; s < 8; ++s) {
        float x = xs[s] * QSC;
        f16 hi = (f16)x;
        qfh[qt][kc][s] = hi;
        qfl[qt][kc][s] = (f16)(x - (float)hi);
      }
    }
  }

  float Mq[2];
  Mq[0] = Mf[hbase + t0 + c];
  Mq[1] = Mf[hbase + t0 + 16 + c];

  const f32x4 z4 = {0.f, 0.f, 0.f, 0.f};
  f32x4 hacc[2][8];
#pragma unroll
  for (int qt = 0; qt < 2; ++qt)
#pragma unroll
    for (int et = 0; et < 8; ++et) hacc[qt][et] = z4;
  float qn[2] = {0.f, 0.f};

  const int n_iters = qt32 / 4 + 1;
  for (int it = 0; it < n_iters; ++it) {
    const int s0 = it * KT;
    __syncthreads();   // prev iteration's fragment reads done before restage

    // ---- stage K hi/lo (row-major, swizzled) ----
    {
      const int colq = tid & 31;   // d-quad
      const int r0 = tid >> 5;     // 0..7
#pragma unroll
      for (int pass = 0; pass < 16; ++pass) {
        const int row = pass * 8 + r0;
        float4 kv4 = *(const float4*)(kg_h + (size_t)(s0 + row) * DHD + colq * 4);
        float xs[4] = {kv4.x, kv4.y, kv4.z, kv4.w};
        f16x4 hi, lo;
#pragma unroll
        for (int s = 0; s < 4; ++s) { f16 h = (f16)xs[s]; hi[s] = h; lo[s] = (f16)(xs[s] - (float)h); }
        const int byte = kswz(row, colq * 8);
        *(f16x4*)(smem + KH_OFF + byte) = hi;
        *(f16x4*)(smem + KL_OFF + byte) = lo;
      }
      // ---- stage V transposed hi/lo ([e][kv], swizzled) ----
      const int e   = tid & 127;
      const int kq0 = tid >> 7;    // 0..1
#pragma unroll
      for (int pass = 0; pass < 16; ++pass) {
        const int kvq = pass * 2 + kq0;
        const int kvb = kvq * 4;
        float xs[4];
#pragma unroll
        for (int r = 0; r < 4; ++r) xs[r] = vg_h[(size_t)(s0 + kvb + r) * DHD + e];
        f16x4 hi, lo;
#pragma unroll
        for (int s = 0; s < 4; ++s) { f16 h = (f16)xs[s]; hi[s] = h; lo[s] = (f16)(xs[s] - (float)h); }
        const int byte = vswz(e, kvq * 8);
        *(f16x4*)(smem + VTH_OFF + byte) = hi;
        *(f16x4*)(smem + VTL_OFF + byte) = lo;
      }
      if (tid < 128) bs_lds[tid] = bf[hbase + s0 + tid];
    }
    __syncthreads();

    // ---- swapped QK^T: D = mfma(K, Q) -> lane holds q=c, kv=4g+r ----
    f32x4 sacc[2][2];
    sacc[0][0] = z4; sacc[0][1] = z4; sacc[1][0] = z4; sacc[1][1] = z4;
    const int kvrow = 32 * w + c;
#pragma unroll
    for (int kc = 0; kc < 4; ++kc) {
      const int cb = kc * 64 + 16 * g;
      f16x8 kh0 = *(const f16x8*)(smem + KH_OFF + kswz(kvrow,      cb));
      f16x8 kl0 = *(const f16x8*)(smem + KL_OFF + kswz(kvrow,      cb));
      f16x8 kh1 = *(const f16x8*)(smem + KH_OFF + kswz(kvrow + 16, cb));
      f16x8 kl1 = *(const f16x8*)(smem + KL_OFF + kswz(kvrow + 16, cb));
#pragma unroll
      for (int qt = 0; qt < 2; ++qt) {
        sacc[qt][0] = mfma16(kh0, qfh[qt][kc], sacc[qt][0]);
        sacc[qt][0] = mfma16(kh0, qfl[qt][kc], sacc[qt][0]);
        sacc[qt][0] = mfma16(kl0, qfh[qt][kc], sacc[qt][0]);
        sacc[qt][1] = mfma16(kh1, qfh[qt][kc], sacc[qt][1]);
        sacc[qt][1] = mfma16(kh1, qfl[qt][kc], sacc[qt][1]);
        sacc[qt][1] = mfma16(kl1, qfh[qt][kc], sacc[qt][1]);
      }
    }

    // ---- weights P = exp(b_s - M_q) * S, causal mask, split to fp16 frags --
    f32x4 b0 = *(const f32x4*)(bs_lds + 32 * w + 4 * g);
    f32x4 b1 = *(const f32x4*)(bs_lds + 32 * w + 16 + 4 * g);
    f16x8 pfh[2], pfl[2];
#pragma unroll
    for (int qt = 0; qt < 2; ++qt) {
      const int qglob = t0 + 16 * qt + c;
#pragma unroll
      for (int r = 0; r < 4; ++r) {
        const int kv0 = s0 + 32 * w + 4 * g + r;
        const int kv1 = kv0 + 16;
        float p0 = (kv0 <= qglob) ? __expf(b0[r] - Mq[qt]) * sacc[qt][0][r] : 0.f;
        float p1 = (kv1 <= qglob) ? __expf(b1[r] - Mq[qt]) * sacc[qt][1][r] : 0.f;
        qn[qt] += p0 + p1;
        f16 h0 = (f16)p0; pfh[qt][r]     = h0; pfl[qt][r]     = (f16)(p0 - (float)h0);
        f16 h1 = (f16)p1; pfh[qt][r + 4] = h1; pfl[qt][r + 4] = (f16)(p1 - (float)h1);
      }
    }

    // ---- PV: A = P (in-register, sigma_p), B = V^T frags from LDS ----
#pragma unroll
    for (int et = 0; et < 8; ++et) {
      const int e = 16 * et + c;
      const int b0b = (32 * w + 4 * g) * 2;
      const int b1b = (32 * w + 16 + 4 * g) * 2;
      f16x4 vh0 = *(const f16x4*)(smem + VTH_OFF + vswz(e, b0b));
      f16x4 vh1 = *(const f16x4*)(smem + VTH_OFF + vswz(e, b1b));
      f16x4 vl0 = *(const f16x4*)(smem + VTL_OFF + vswz(e, b0b));
      f16x4 vl1 = *(const f16x4*)(smem + VTL_OFF + vswz(e, b1b));
      f16x8 vfh, vfl;
#pragma unroll
      for (int s = 0; s < 4; ++s) {
        vfh[s] = vh0[s]; vfh[s + 4] = vh1[s];
        vfl[s] = vl0[s]; vfl[s + 4] = vl1[s];
      }
#pragma unroll
      for (int qt = 0; qt < 2; ++qt) {
        hacc[qt][et] = mfma16(pfh[qt], vfh, hacc[qt][et]);
        hacc[qt][et] = mfma16(pfh[qt], vfl, hacc[qt][et]);
        hacc[qt][et] = mfma16(pfl[qt], vfh, hacc[qt][et]);
      }
    }
  }

  // ---- epilogue: cross-wave reduction + normalize ----
#pragma unroll
  for (int qt = 0; qt < 2; ++qt) {
    qn[qt] += __shfl_xor(qn[qt], 16);
    qn[qt] += __shfl_xor(qn[qt], 32);
  }
  __syncthreads();   // all LDS fragment reads done before repurposing smem
  float* qnl  = (float*)(smem + QNL_OFF);
  float* part = (float*)(smem + PART_OFF);
  if (lane < 16) { qnl[w * 32 + lane] = qn[0]; qnl[w * 32 + 16 + lane] = qn[1]; }
#pragma unroll
  for (int qt = 0; qt < 2; ++qt)
#pragma unroll
    for (int et = 0; et < 8; ++et)
#pragma unroll
      for (int r = 0; r < 4; ++r)
        part[(w * 32 + 16 * qt + 4 * g + r) * 132 + 16 * et + c] = hacc[qt][et][r];
  __syncthreads();

  const int e4 = (tid & 31) * 4;
#pragma unroll
  for (int pass = 0; pass < 4; ++pass) {
    const int q = pass * 8 + (tid >> 5);
    f32x4 s = {0.f, 0.f, 0.f, 0.f};
#pragma unroll
    for (int wv = 0; wv < 4; ++wv) {
      const float* pp = part + (wv * 32 + q) * 132 + e4;
      s[0] += pp[0]; s[1] += pp[1]; s[2] += pp[2]; s[3] += pp[3];
    }
    const float qns = qnl[q] + qnl[32 + q] + qnl[64 + q] + qnl[96 + q];
    const float den = fmaxf(fabsf(qns), en[hbase + t0 + q]) + EPS;
    const float inv = 1.0f / den;
    float4 o = make_float4(s[0] * inv, s[1] * inv, s[2] * inv, s[3] * inv);
    *(float4*)(outg + (hbase + t0 + q) * DHD + e4) = o;
  }
}

extern "C" void kernel_launch(void* const* d_in, const int* in_sizes, int n_in,
                              void* d_out, int out_size, void* d_ws, size_t ws_size,
                              hipStream_t stream) {
  (void)in_sizes; (void)n_in; (void)out_size; (void)ws_size;
  const float* q  = (const float*)d_in[0];
  const float* k  = (const float*)d_in[1];
  const float* v  = (const float*)d_in[2];
  const float* ii = (const float*)d_in[3];
  const float* ff = (const float*)d_in[4];
  float* out = (float*)d_out;

  float* bf = (float*)d_ws;                 // f32 [8][2048] b_s
  float* Mf = bf + NHEADS * S_LEN;          // f32 [8][2048] M_t
  float* en = Mf + NHEADS * S_LEN;          // f32 [8][2048] exp(-m_t)

  hipFuncSetAttribute(reinterpret_cast<const void*>(mlstm_main),
                      hipFuncAttributeMaxDynamicSharedMemorySize, SMEM_BYTES);
  mlstm_scan<<<dim3(NHEADS), dim3(256), 0, stream>>>(ii, ff, bf, Mf, en);
  mlstm_main<<<dim3(512), dim3(256), SMEM_BYTES, stream>>>(q, k, v, bf, Mf, en, out);
}

// Round 4
// 159.836 us; speedup vs baseline: 3.8188x; 1.0406x over previous
//
#include <hip/hip_runtime.h>
#include <math.h>

// mLSTM parallel closed form:
//   F_t = prefix_sum(log_sigmoid(f)),  b_s = i_s - F_s,
//   M_t = max(0, prefix_max(b)_t),  m_t = F_t + M_t,
//   w[t,s] = exp(b_s - M_t)  (s <= t, always <= 1),
//   h_t = (sum_s w*(q.k_s)*v_s) / (max(|sum_s w*(q.k_s)|, exp(-m_t)) + 1e-6)
//
// R4: prepass pre-splits K (hi/lo fp16, swizzled) and pre-transposes V
// (hi/lo fp16, swizzled) into d_ws panels; main kernel stages via
// global_load_lds (pure memcpy), KT=64, 66KB LDS -> 2 blocks/CU.
// Fallback to the R3 kernel if ws_size is too small for the panels.

typedef _Float16 f16;
typedef _Float16 f16x4 __attribute__((ext_vector_type(4)));
typedef _Float16 f16x8 __attribute__((ext_vector_type(8)));
typedef float    f32x4 __attribute__((ext_vector_type(4)));

#define S_LEN  2048
#define DHD    128
#define NHEADS 8
#define EPS    1e-6f

// ---------- fast-path LDS offsets (KT=64) ----------
#define KHI_F 0        // fp16 [64][128] K hi, swizzled rows (256B)
#define KLO_F 16384
#define VHI_F 32768    // fp16 [128 e][64 kv] V^T hi, swizzled rows (128B)
#define VLO_F 49152
#define BS_F  65536    // f32 [64]
#define QNL_F 65792    // f32 [2 wk][2 qh][16]
#define SMEM_FAST 66048

__device__ __forceinline__ int kswz(int row, int byteInRow) {
  // 256B rows: XOR row-bits into 16B-granule index -> conflict-free b128 frag reads
  return row * 256 + (byteInRow ^ ((row & 15) << 4));
}
__device__ __forceinline__ int vswz64(int e, int byteInRow) {
  // 128B rows ([e][64 kv] fp16): spread 16 e-rows across all banks for b64 reads
  return e * 128 + (byteInRow ^ ((e & 15) << 3));
}
__device__ __forceinline__ f32x4 mfma16(f16x8 a, f16x8 b, f32x4 c) {
  return __builtin_amdgcn_mfma_f32_16x16x32_f16(a, b, c, 0, 0, 0);
}
__device__ __forceinline__ void gload16(const void* g, void* l) {
  __builtin_amdgcn_global_load_lds((const __attribute__((address_space(1))) unsigned int*)g,
                                   (__attribute__((address_space(3))) unsigned int*)l, 16, 0, 0);
}

// ---------------- scan prepass: b_s, M_t, exp(-m_t) (fp64 internal) --------
__global__ __launch_bounds__(256) void mlstm_scan(
    const float* __restrict__ ig_all, const float* __restrict__ fg_all,
    float* __restrict__ bf, float* __restrict__ Mf, float* __restrict__ en)
{
  const int hd  = blockIdx.x;
  const int tid = threadIdx.x;
  __shared__ double sc[256];
  const float* fg = fg_all + (size_t)hd * S_LEN;
  const float* ig = ig_all + (size_t)hd * S_LEN;
  const int base = tid * 8;

  double v[8];
#pragma unroll
  for (int u = 0; u < 8; ++u) {
    float x = fg[base + u];
    float fl = fminf(x, 0.0f) - log1pf(expf(-fabsf(x)));  // stable log_sigmoid
    v[u] = (double)fl;
  }
#pragma unroll
  for (int u = 1; u < 8; ++u) v[u] += v[u - 1];
  sc[tid] = v[7];
  __syncthreads();
  for (int off = 1; off < 256; off <<= 1) {
    double t = (tid >= off) ? sc[tid - off] : 0.0;
    __syncthreads();
    sc[tid] += t;
    __syncthreads();
  }
  const double excl = sc[tid] - v[7];

  double F[8], b[8];
#pragma unroll
  for (int u = 0; u < 8; ++u) {
    F[u] = v[u] + excl;
    b[u] = (double)ig[base + u] - F[u];
    bf[(size_t)hd * S_LEN + base + u] = (float)b[u];
  }
  __syncthreads();
  double mv[8];
  mv[0] = b[0];
#pragma unroll
  for (int u = 1; u < 8; ++u) mv[u] = fmax(mv[u - 1], b[u]);
  sc[tid] = mv[7];
  __syncthreads();
  for (int off = 1; off < 256; off <<= 1) {
    double t = (tid >= off) ? sc[tid - off] : -1.0e300;
    __syncthreads();
    sc[tid] = fmax(sc[tid], t);
    __syncthreads();
  }
  const double exclm = (tid > 0) ? sc[tid - 1] : -1.0e300;
  double run = exclm;
#pragma unroll
  for (int u = 0; u < 8; ++u) {
    run = fmax(run, b[u]);
    double Mt = fmax(0.0, run);       // m0=0 carry path
    Mf[(size_t)hd * S_LEN + base + u] = (float)Mt;
    en[(size_t)hd * S_LEN + base + u] = (float)exp(-(F[u] + Mt));
  }
}

// ---------------- prepass: K -> Khi/Klo fp16 panels, swizzled rows ---------
__global__ __launch_bounds__(256) void prep_k(
    const float* __restrict__ kg, char* __restrict__ gkh, char* __restrict__ gkl)
{
  const int gid  = blockIdx.x * 256 + threadIdx.x;   // 65536 threads
  const int row  = gid >> 2;                         // 0..16383 (head*2048+kv)
  const int part = gid & 3;
  const float* src = kg + (size_t)row * DHD;
  char* oh = gkh + (size_t)row * 256;
  char* ol = gkl + (size_t)row * 256;
#pragma unroll
  for (int j = 0; j < 8; ++j) {
    float4 x = *(const float4*)(src + j * 16 + part * 4);
    float xs[4] = {x.x, x.y, x.z, x.w};
    f16x4 hi, lo;
#pragma unroll
    for (int s = 0; s < 4; ++s) { f16 h = (f16)xs[s]; hi[s] = h; lo[s] = (f16)(xs[s] - (float)h); }
    const int byte = (j * 32 + part * 8) ^ ((row & 15) << 4);
    *(f16x4*)(oh + byte) = hi;
    *(f16x4*)(ol + byte) = lo;
  }
}

// ---------------- prepass: V -> transposed VT hi/lo fp16 tiles, swizzled ---
__global__ __launch_bounds__(256) void prep_vt(
    const float* __restrict__ vg, char* __restrict__ gvh, char* __restrict__ gvl)
{
  __shared__ float vts[64][132];
  const int bid = blockIdx.x;         // 256 = 8 heads x 32 tiles
  const int head = bid >> 5;
  const int it   = bid & 31;
  const int tid  = threadIdx.x;

  // load V tile [64 kv][128 e] coalesced
  {
    const int r   = tid >> 2;
    const int seg = tid & 3;
    const float* src = vg + ((size_t)(head * S_LEN + it * 64 + r)) * DHD;
#pragma unroll
    for (int j = 0; j < 8; ++j) {
      const int c4 = j * 16 + seg * 4;
      *(float4*)&vts[r][c4] = *(const float4*)(src + c4);
    }
  }
  __syncthreads();

  // write transposed hi/lo at swizzled offsets
  const int e = tid >> 1;
  const int h = tid & 1;
  const size_t tb = (size_t)(head * 32 + it) * 16384 + (size_t)e * 128;
#pragma unroll
  for (int i4 = 0; i4 < 8; ++i4) {
    f16x4 hi, lo;
#pragma unroll
    for (int s = 0; s < 4; ++s) {
      float x = vts[32 * h + i4 * 4 + s][e];
      f16 hh = (f16)x; hi[s] = hh; lo[s] = (f16)(x - (float)hh);
    }
    const int byte = ((32 * h + i4 * 4) * 2) ^ ((e & 15) << 3);
    *(f16x4*)(gvh + tb + byte) = hi;
    *(f16x4*)(gvl + tb + byte) = lo;
  }
}

// ---------------- fast main kernel: KT=64, memcpy staging, 2 blocks/CU -----
__global__ __launch_bounds__(256, 2) void mlstm_fast(
    const float* __restrict__ qg,
    const char* __restrict__ gkh, const char* __restrict__ gkl,
    const char* __restrict__ gvh, const char* __restrict__ gvl,
    const float* __restrict__ bf, const float* __restrict__ Mf,
    const float* __restrict__ en, float* __restrict__ outg)
{
  extern __shared__ char smem[];
  const int bid  = blockIdx.x;
  const int hd   = bid & 7;            // head i -> XCD i (L2-resident panels)
  const int idx  = bid >> 3;           // 0..63
  // pairing permutation: blocks b and b+256 (same CU slot) sum to 33 iters
  const int qt32 = (idx < 32) ? (63 - 2 * idx) : (2 * (idx - 32));
  const int t0   = qt32 * 32;
  const int tid  = threadIdx.x;
  const int w    = tid >> 6;
  const int lane = tid & 63;
  const int c    = lane & 15;
  const int g    = lane >> 4;
  const int wk   = w & 1;              // kv-half of the tile (32 rows)
  const int qh   = w >> 1;             // q-half of the block (16 rows)

  const size_t hbase = (size_t)hd * S_LEN;
  float* bs_lds = (float*)(smem + BS_F);

  // ---- Q fragments (hi/lo split) for this wave's q-half ----
  constexpr float QSC = 0.08838834764831845f;
  f16x8 qfh[4], qfl[4];
  {
    const float* qrow = qg + (hbase + t0 + 16 * qh + c) * DHD;
#pragma unroll
    for (int kc = 0; kc < 4; ++kc) {
      const float* p = qrow + kc * 32 + 8 * g;
      float4 a = *(const float4*)p;
      float4 b = *(const float4*)(p + 4);
      float xs[8] = {a.x, a.y, a.z, a.w, b.x, b.y, b.z, b.w};
#pragma unroll
      for (int s = 0; s < 8; ++s) {
        float x = xs[s] * QSC;
        f16 hi = (f16)x;
        qfh[kc][s] = hi;
        qfl[kc][s] = (f16)(x - (float)hi);
      }
    }
  }
  const float Mq = Mf[hbase + t0 + 16 * qh + c];

  const f32x4 z4 = {0.f, 0.f, 0.f, 0.f};
  f32x4 hacc[8];
#pragma unroll
  for (int et = 0; et < 8; ++et) hacc[et] = z4;
  float qn = 0.f;

  const char* pkh = gkh + hbase * 256;        // per-head K panel (512KB)
  const char* pkl = gkl + hbase * 256;
  const char* pvh = gvh + (size_t)hd * 524288; // per-head VT panel (512KB)
  const char* pvl = gvl + (size_t)hd * 524288;

  const int n_iters = qt32 / 2 + 1;
  for (int it = 0; it < n_iters; ++it) {
    const int s0 = it * 64;
    __syncthreads();   // prev iteration's fragment reads done before restage

    // ---- stage 64KB via global_load_lds (pure memcpy, no VALU) ----
    {
      const size_t tb = (size_t)it * 16384;
#pragma unroll
      for (int u = 0; u < 4; ++u) {
        const int off = (w << 12) + (u << 10);
        const int gl  = off + lane * 16;
        gload16(pkh + tb + gl, smem + KHI_F + off);
        gload16(pkl + tb + gl, smem + KLO_F + off);
        gload16(pvh + tb + gl, smem + VHI_F + off);
        gload16(pvl + tb + gl, smem + VLO_F + off);
      }
      if (tid < 64) bs_lds[tid] = bf[hbase + s0 + tid];
    }
    __syncthreads();

    // ---- swapped QK^T: D = mfma(K, Q); lane holds q=c, kv=32wk+{4g+r,16+4g+r}
    f32x4 sacc0 = z4, sacc1 = z4;
    const int rowA = 32 * wk + c;
#pragma unroll
    for (int kc = 0; kc < 4; ++kc) {
      const int cb = kc * 64 + 16 * g;
      f16x8 kh0 = *(const f16x8*)(smem + KHI_F + kswz(rowA,      cb));
      f16x8 kl0 = *(const f16x8*)(smem + KLO_F + kswz(rowA,      cb));
      f16x8 kh1 = *(const f16x8*)(smem + KHI_F + kswz(rowA + 16, cb));
      f16x8 kl1 = *(const f16x8*)(smem + KLO_F + kswz(rowA + 16, cb));
      sacc0 = mfma16(kh0, qfh[kc], sacc0);
      sacc0 = mfma16(kh0, qfl[kc], sacc0);
      sacc0 = mfma16(kl0, qfh[kc], sacc0);
      sacc1 = mfma16(kh1, qfh[kc], sacc1);
      sacc1 = mfma16(kh1, qfl[kc], sacc1);
      sacc1 = mfma16(kl1, qfh[kc], sacc1);
    }

    // ---- P = exp(b_s - M_q) * S, causal mask, split to fp16 frags ----
    f32x4 b0 = *(const f32x4*)(bs_lds + 32 * wk + 4 * g);
    f32x4 b1 = *(const f32x4*)(bs_lds + 32 * wk + 16 + 4 * g);
    const int qglob = t0 + 16 * qh + c;
    f16x8 pfh, pfl;
#pragma unroll
    for (int r = 0; r < 4; ++r) {
      const int kv0 = s0 + 32 * wk + 4 * g + r;
      const int kv1 = kv0 + 16;
      float p0 = (kv0 <= qglob) ? __expf(b0[r] - Mq) * sacc0[r] : 0.f;
      float p1 = (kv1 <= qglob) ? __expf(b1[r] - Mq) * sacc1[r] : 0.f;
      qn += p0 + p1;
      f16 h0 = (f16)p0; pfh[r]     = h0; pfl[r]     = (f16)(p0 - (float)h0);
      f16 h1 = (f16)p1; pfh[r + 4] = h1; pfl[r + 4] = (f16)(p1 - (float)h1);
    }

    // ---- PV: A = P (in-register), B = V^T frags from LDS ----
    const int byte0 = (64 * wk + 8 * g)      ^ (c << 3);
    const int byte1 = (64 * wk + 32 + 8 * g) ^ (c << 3);
#pragma unroll
    for (int et = 0; et < 8; ++et) {
      const int eb = (16 * et + c) * 128;
      f16x4 vh0 = *(const f16x4*)(smem + VHI_F + eb + byte0);
      f16x4 vh1 = *(const f16x4*)(smem + VHI_F + eb + byte1);
      f16x4 vl0 = *(const f16x4*)(smem + VLO_F + eb + byte0);
      f16x4 vl1 = *(const f16x4*)(smem + VLO_F + eb + byte1);
      f16x8 vfh, vfl;
#pragma unroll
      for (int s = 0; s < 4; ++s) {
        vfh[s] = vh0[s]; vfh[s + 4] = vh1[s];
        vfl[s] = vl0[s]; vfl[s + 4] = vl1[s];
      }
      hacc[et] = mfma16(pfh, vfh, hacc[et]);
      hacc[et] = mfma16(pfh, vfl, hacc[et]);
      hacc[et] = mfma16(pfl, vfh, hacc[et]);
    }
  }

  // ---- epilogue: reduce across wk pair, normalize, store ----
  qn += __shfl_xor(qn, 16);
  qn += __shfl_xor(qn, 32);
  __syncthreads();
  float* qnl  = (float*)(smem + QNL_F);
  float* part = (float*)smem;          // [2 wk][32 q][132]
  if (lane < 16) qnl[(wk * 2 + qh) * 16 + lane] = qn;
#pragma unroll
  for (int et = 0; et < 8; ++et)
#pragma unroll
    for (int r = 0; r < 4; ++r)
      part[(wk * 32 + 16 * qh + 4 * g + r) * 132 + 16 * et + c] = hacc[et][r];
  __syncthreads();

  const int e4 = (tid & 31) * 4;
#pragma unroll
  for (int pass = 0; pass < 4; ++pass) {
    const int q = pass * 8 + (tid >> 5);
    const float* pa = part + q * 132 + e4;
    const float* pb = part + (32 + q) * 132 + e4;
    f32x4 s;
#pragma unroll
    for (int s_ = 0; s_ < 4; ++s_) s[s_] = pa[s_] + pb[s_];
    const int qhh = q >> 4;
    const float qns = qnl[qhh * 16 + (q & 15)] + qnl[(2 + qhh) * 16 + (q & 15)];
    const float den = fmaxf(fabsf(qns), en[hbase + t0 + q]) + EPS;
    const float inv = 1.0f / den;
    float4 o = make_float4(s[0] * inv, s[1] * inv, s[2] * inv, s[3] * inv);
    *(float4*)(outg + (hbase + t0 + q) * DHD + e4) = o;
  }
}

// =================== R3 fallback (used only if ws_size too small) ==========
#define KH_OFF  0
#define KL_OFF  32768
#define VTH_OFF 65536
#define VTL_OFF 98304
#define BS_OFF  131072
#define QNL_OFF 131712
#define SMEM_FB 132224

__device__ __forceinline__ int vswzfb(int e, int byteInRow) {
  return e * 256 + (byteInRow ^ ((e & 15) << 4) ^ (((e >> 4) & 1) << 3));
}

__global__ __launch_bounds__(256, 1) void mlstm_main_fb(
    const float* __restrict__ qg, const float* __restrict__ kg, const float* __restrict__ vg,
    const float* __restrict__ bf, const float* __restrict__ Mf, const float* __restrict__ en,
    float* __restrict__ outg)
{
  extern __shared__ char smem[];
  const int bid  = blockIdx.x;
  const int hd   = bid & 7;
  const int qt32 = 63 - (bid >> 3);
  const int t0   = qt32 * 32;
  const int tid  = threadIdx.x;
  const int w    = tid >> 6;
  const int lane = tid & 63;
  const int c    = lane & 15;
  const int g    = lane >> 4;

  const size_t hbase = (size_t)hd * S_LEN;
  const float* qg_h = qg + (hbase + t0) * DHD;
  const float* kg_h = kg + hbase * DHD;
  const float* vg_h = vg + hbase * DHD;
  float* bs_lds = (float*)(smem + BS_OFF);

  constexpr float QSC = 0.08838834764831845f;
  f16x8 qfh[2][4], qfl[2][4];
#pragma unroll
  for (int qt = 0; qt < 2; ++qt) {
    const float* qrow = qg_h + (size_t)(16 * qt + c) * DHD;
#pragma unroll
    for (int kc = 0; kc < 4; ++kc) {
      const float* p = qrow + kc * 32 + 8 * g;
      float4 a = *(const float4*)p;
      float4 b = *(const float4*)(p + 4);
      float xs[8] = {a.x, a.y, a.z, a.w, b.x, b.y, b.z, b.w};
#pragma unroll
      for (int s = 0; s < 8; ++s) {
        float x = xs[s] * QSC;
        f16 hi = (f16)x;
        qfh[qt][kc][s] = hi;
        qfl[qt][kc][s] = (f16)(x - (float)hi);
      }
    }
  }
  float Mq[2];
  Mq[0] = Mf[hbase + t0 + c];
  Mq[1] = Mf[hbase + t0 + 16 + c];

  const f32x4 z4 = {0.f, 0.f, 0.f, 0.f};
  f32x4 hacc[2][8];
#pragma unroll
  for (int qt = 0; qt < 2; ++qt)
#pragma unroll
    for (int et = 0; et < 8; ++et) hacc[qt][et] = z4;
  float qn[2] = {0.f, 0.f};

  const int n_iters = qt32 / 4 + 1;
  for (int it = 0; it < n_iters; ++it) {
    const int s0 = it * 128;
    __syncthreads();
    {
      const int colq = tid & 31;
      const int r0 = tid >> 5;
#pragma unroll
      for (int pass = 0; pass < 16; ++pass) {
        const int row = pass * 8 + r0;
        float4 kv4 = *(const float4*)(kg_h + (size_t)(s0 + row) * DHD + colq * 4);
        float xs[4] = {kv4.x, kv4.y, kv4.z, kv4.w};
        f16x4 hi, lo;
#pragma unroll
        for (int s = 0; s < 4; ++s) { f16 h = (f16)xs[s]; hi[s] = h; lo[s] = (f16)(xs[s] - (float)h); }
        const int byte = kswz(row, colq * 8);
        *(f16x4*)(smem + KH_OFF + byte) = hi;
        *(f16x4*)(smem + KL_OFF + byte) = lo;
      }
      const int e   = tid & 127;
      const int kq0 = tid >> 7;
#pragma unroll
      for (int pass = 0; pass < 16; ++pass) {
        const int kvq = pass * 2 + kq0;
        const int kvb = kvq * 4;
        float xs[4];
#pragma unroll
        for (int r = 0; r < 4; ++r) xs[r] = vg_h[(size_t)(s0 + kvb + r) * DHD + e];
        f16x4 hi, lo;
#pragma unroll
        for (int s = 0; s < 4; ++s) { f16 h = (f16)xs[s]; hi[s] = h; lo[s] = (f16)(xs[s] - (float)h); }
        const int byte = vswzfb(e, kvq * 8);
        *(f16x4*)(smem + VTH_OFF + byte) = hi;
        *(f16x4*)(smem + VTL_OFF + byte) = lo;
      }
      if (tid < 128) bs_lds[tid] = bf[hbase + s0 + tid];
    }
    __syncthreads();

    f32x4 sacc[2][2];
    sacc[0][0] = z4; sacc[0][1] = z4; sacc[1][0] = z4; sacc[1][1] = z4;
    const int kvrow = 32 * w + c;
#pragma unroll
    for (int kc = 0; kc < 4; ++kc) {
      const int cb = kc * 64 + 16 * g;
      f16x8 kh0 = *(const f16x8*)(smem + KH_OFF + kswz(kvrow,      cb));
      f16x8 kl0 = *(const f16x8*)(smem + KL_OFF + kswz(kvrow,      cb));
      f16x8 kh1 = *(const f16x8*)(smem + KH_OFF + kswz(kvrow + 16, cb));
      f16x8 kl1 = *(const f16x8*)(smem + KL_OFF + kswz(kvrow + 16, cb));
#pragma unroll
      for (int qt = 0; qt < 2; ++qt) {
        sacc[qt][0] = mfma16(kh0, qfh[qt][kc], sacc[qt][0]);
        sacc[qt][0] = mfma16(kh0, qfl[qt][kc], sacc[qt][0]);
        sacc[qt][0] = mfma16(kl0, qfh[qt][kc], sacc[qt][0]);
        sacc[qt][1] = mfma16(kh1, qfh[qt][kc], sacc[qt][1]);
        sacc[qt][1] = mfma16(kh1, qfl[qt][kc], sacc[qt][1]);
        sacc[qt][1] = mfma16(kl1, qfh[qt][kc], sacc[qt][1]);
      }
    }

    f32x4 b0 = *(const f32x4*)(bs_lds + 32 * w + 4 * g);
    f32x4 b1 = *(const f32x4*)(bs_lds + 32 * w + 16 + 4 * g);
    f16x8 pfh[2], pfl[2];
#pragma unroll
    for (int qt = 0; qt < 2; ++qt) {
      const int qglob = t0 + 16 * qt + c;
#pragma unroll
      for (int r = 0; r < 4; ++r) {
        const int kv0 = s0 + 32 * w + 4 * g + r;
        const int kv1 = kv0 + 16;
        float p0 = (kv0 <= qglob) ? __expf(b0[r] - Mq[qt]) * sacc[qt][0][r] : 0.f;
        float p1 = (kv1 <= qglob) ? __expf(b1[r] - Mq[qt]) * sacc[qt][1][r] : 0.f;
        qn[qt] += p0 + p1;
        f16 h0 = (f16)p0; pfh[qt][r]     = h0; pfl[qt][r]     = (f16)(p0 - (float)h0);
        f16 h1 = (f16)p1; pfh[qt][r + 4] = h1; pfl[qt][r + 4] = (f16)(p1 - (float)h1);
      }
    }

#pragma unroll
    for (int et = 0; et < 8; ++et) {
      const int e = 16 * et + c;
      const int b0b = (32 * w + 4 * g) * 2;
      const int b1b = (32 * w + 16 + 4 * g) * 2;
      f16x4 vh0 = *(const f16x4*)(smem + VTH_OFF + vswzfb(e, b0b));
      f16x4 vh1 = *(const f16x4*)(smem + VTH_OFF + vswzfb(e, b1b));
      f16x4 vl0 = *(const f16x4*)(smem + VTL_OFF + vswzfb(e, b0b));
      f16x4 vl1 = *(const f16x4*)(smem + VTL_OFF + vswzfb(e, b1b));
      f16x8 vfh, vfl;
#pragma unroll
      for (int s = 0; s < 4; ++s) {
        vfh[s] = vh0[s]; vfh[s + 4] = vh1[s];
        vfl[s] = vl0[s]; vfl[s + 4] = vl1[s];
      }
#pragma unroll
      for (int qt = 0; qt < 2; ++qt) {
        hacc[qt][et] = mfma16(pfh[qt], vfh, hacc[qt][et]);
        hacc[qt][et] = mfma16(pfh[qt], vfl, hacc[qt][et]);
        hacc[qt][et] = mfma16(pfl[qt], vfh, hacc[qt][et]);
      }
    }
  }

#pragma unroll
  for (int qt = 0; qt < 2; ++qt) {
    qn[qt] += __shfl_xor(qn[qt], 16);
    qn[qt] += __shfl_xor(qn[qt], 32);
  }
  __syncthreads();
  float* qnl  = (float*)(smem + QNL_OFF);
  float* part = (float*)smem;
  if (lane < 16) { qnl[w * 32 + lane] = qn[0]; qnl[w * 32 + 16 + lane] = qn[1]; }
#pragma unroll
  for (int qt = 0; qt < 2; ++qt)
#pragma unroll
    for (int et = 0; et < 8; ++et)
#pragma unroll
      for (int r = 0; r < 4; ++r)
        part[(w * 32 + 16 * qt + 4 * g + r) * 132 + 16 * et + c] = hacc[qt][et][r];
  __syncthreads();

  const int e4 = (tid & 31) * 4;
#pragma unroll
  for (int pass = 0; pass < 4; ++pass) {
    const int q = pass * 8 + (tid >> 5);
    f32x4 s = {0.f, 0.f, 0.f, 0.f};
#pragma unroll
    for (int wv = 0; wv < 4; ++wv) {
      const float* pp = part + (wv * 32 + q) * 132 + e4;
      s[0] += pp[0]; s[1] += pp[1]; s[2] += pp[2]; s[3] += pp[3];
    }
    const float qns = qnl[q] + qnl[32 + q] + qnl[64 + q] + qnl[96 + q];
    const float den = fmaxf(fabsf(qns), en[hbase + t0 + q]) + EPS;
    const float inv = 1.0f / den;
    float4 o = make_float4(s[0] * inv, s[1] * inv, s[2] * inv, s[3] * inv);
    *(float4*)(outg + (hbase + t0 + q) * DHD + e4) = o;
  }
}

extern "C" void kernel_launch(void* const* d_in, const int* in_sizes, int n_in,
                              void* d_out, int out_size, void* d_ws, size_t ws_size,
                              hipStream_t stream) {
  (void)in_sizes; (void)n_in; (void)out_size;
  const float* q  = (const float*)d_in[0];
  const float* k  = (const float*)d_in[1];
  const float* v  = (const float*)d_in[2];
  const float* ii = (const float*)d_in[3];
  const float* ff = (const float*)d_in[4];
  float* out = (float*)d_out;

  float* bf = (float*)d_ws;                 // f32 [8][2048]
  float* Mf = bf + NHEADS * S_LEN;
  float* en = Mf + NHEADS * S_LEN;          // ends at 192KB

  const size_t PANEL = 4u * 1024 * 1024;    // 4MB per panel
  const size_t need  = 3u * NHEADS * S_LEN * 4 + 4 * PANEL;  // 192KB + 16MB

  mlstm_scan<<<dim3(NHEADS), dim3(256), 0, stream>>>(ii, ff, bf, Mf, en);

  if (ws_size >= need) {
    char* gkh = (char*)(en + NHEADS * S_LEN);
    char* gkl = gkh + PANEL;
    char* gvh = gkl + PANEL;
    char* gvl = gvh + PANEL;
    hipFuncSetAttribute(reinterpret_cast<const void*>(mlstm_fast),
                        hipFuncAttributeMaxDynamicSharedMemorySize, SMEM_FAST);
    prep_k <<<dim3(256), dim3(256), 0, stream>>>(k, gkh, gkl);
    prep_vt<<<dim3(256), dim3(256), 0, stream>>>(v, gvh, gvl);
    mlstm_fast<<<dim3(512), dim3(256), SMEM_FAST, stream>>>(
        q, gkh, gkl, gvh, gvl, bf, Mf, en, out);
  } else {
    hipFuncSetAttribute(reinterpret_cast<const void*>(mlstm_main_fb),
                        hipFuncAttributeMaxDynamicSharedMemorySize, SMEM_FB);
    mlstm_main_fb<<<dim3(512), dim3(256), SMEM_FB, stream>>>(
        q, k, v, bf, Mf, en, out);
  }
}